// Round 2
// baseline (380.364 us; speedup 1.0000x reference)
//
#include <hip/hip_runtime.h>
#include <math.h>

#define BB 16
#define CC 64
#define HH 224
#define WW 224
#define HWSZ (HH * WW)          // 50176
#define HW4 (HWSZ / 4)          // 12544
#define W4 (WW / 4)             // 56
#define R 7                     // gate rows per tile (224/7 = 32 tiles)
#define TILES (HH / R)          // 32
#define FR (R + 6)              // 13 feat rows incl ±3 halo
#define FW 240                  // padded LDS feat row width
#define T 512                   // threads per block (8 waves), kernel B
#define NBLK (BB * TILES)       // 512 blocks = 2 blocks/CU

#define TA 256                  // threads per block, kernel A
#define NPIX (BB * HW4)         // 200704 float4 pixels total
#define NBLKA (NPIX / TA)       // 784 blocks

typedef float f32x4 __attribute__((ext_vector_type(4)));

// ---------------------------------------------------------------------------
// Kernel A: channel mean+max reduction. One thread per float4 pixel.
// Pure read-streamer: x read exactly once (205 MB), feat written once (6.4 MB).
// No LDS, no barriers, no halo duplication. Leaves x resident in the LLC for B.
// ---------------------------------------------------------------------------
__global__ __launch_bounds__(TA) void reduce_kernel(const float* __restrict__ x,
                                                    float* __restrict__ feat) {
    const int idx = blockIdx.x * TA + threadIdx.x;   // 0 .. NPIX-1
    const int b   = idx / HW4;
    const int p   = idx - b * HW4;
    const f32x4* xp = reinterpret_cast<const f32x4*>(x) + (size_t)b * (CC * HW4) + p;

    f32x4 s = {0.f, 0.f, 0.f, 0.f};
    f32x4 m = {-INFINITY, -INFINITY, -INFINITY, -INFINITY};
#pragma unroll 16
    for (int c = 0; c < CC; ++c) {
        f32x4 u = xp[(size_t)c * HW4];
        s += u;
        m[0] = fmaxf(m[0], u[0]); m[1] = fmaxf(m[1], u[1]);
        m[2] = fmaxf(m[2], u[2]); m[3] = fmaxf(m[3], u[3]);
    }
    const float inv = 1.0f / 64.0f;
    f32x4* fav = reinterpret_cast<f32x4*>(feat);          // avg plane [16][HW]
    f32x4* fmx = fav + NPIX;                              // max plane [16][HW]
    fav[idx] = s * inv;
    fmx[idx] = m;
}

// ---------------------------------------------------------------------------
// Kernel B: stage feat tile (23 KB, L2/LLC-hit) -> 7x7 conv + sigmoid -> gate,
// then stream out = x * gate. Dominated by phase-3 streaming; x reads are
// LLC-warm from kernel A, out uses nt stores to avoid evicting x.
// ---------------------------------------------------------------------------
__global__ __launch_bounds__(T, 4) void gate_kernel(const float* __restrict__ x,
                                                    const float* __restrict__ feat,
                                                    const float* __restrict__ cw,
                                                    const float* __restrict__ cb,
                                                    float* __restrict__ out) {
    __shared__ float fa[FR * FW];               // avg plane (zero-padded borders)
    __shared__ float fm[FR * FW];               // max plane
    __shared__ alignas(16) float gate[R * WW];  // sigmoid(conv) result
    __shared__ float wt[98];                    // conv weights [2][7][7]

    // XCD-chunked swizzle (bijective: 512 % 8 == 0): adjacent tiles of one
    // batch share their 6-row feat halo within one XCD's L2.
    const int blk0 = blockIdx.x;
    const int blk  = (blk0 & 7) * (NBLK / 8) + (blk0 >> 3);
    const int b    = blk >> 5;                  // TILES == 32
    const int tb   = blk & 31;
    const int h0   = tb * R;
    const int t    = threadIdx.x;

    for (int i = t; i < FR * FW; i += T) { fa[i] = 0.f; fm[i] = 0.f; }
    if (t < 98) wt[t] = cw[t];
    __syncthreads();

    // ---- phase 1: stage feat rows h0-3 .. h0+R+2 into LDS (1456 float4 loads)
    const f32x4* fav = reinterpret_cast<const f32x4*>(feat) + (size_t)b * HW4;
    const f32x4* fmx = fav + NPIX;
    for (int q = t; q < 2 * FR * W4; q += T) {
        int plane = (q >= FR * W4);
        int p  = plane ? q - FR * W4 : q;
        int pr = p / W4;
        int pc = p - pr * W4;
        int gh = h0 - 3 + pr;
        if ((unsigned)gh >= (unsigned)HH) continue;      // stays zero (padding)
        f32x4 u = (plane ? fmx : fav)[gh * W4 + pc];
        float* dst = (plane ? fm : fa) + pr * FW + 3 + pc * 4;
        dst[0] = u[0]; dst[1] = u[1]; dst[2] = u[2]; dst[3] = u[3];
    }
    __syncthreads();

    // ---- phase 2: 7x7 conv (2->1) + bias + sigmoid -> gate LDS
    const float bias = cb[0];
    for (int p = t; p < R * WW; p += T) {       // 1568 gate pixels
        int r = p / WW;
        int w = p - r * WW;
        float acc = bias;
#pragma unroll
        for (int kh = 0; kh < 7; ++kh) {
            int ro = (r + kh) * FW + w;
#pragma unroll
            for (int kw = 0; kw < 7; ++kw) {
                acc = fmaf(fa[ro + kw], wt[kh * 7 + kw], acc);
                acc = fmaf(fm[ro + kw], wt[49 + kh * 7 + kw], acc);
            }
        }
        gate[p] = 1.0f / (1.0f + expf(-acc));
    }
    __syncthreads();

    // ---- phase 3: out = x * gate for all 64 channels of this tile
    const f32x4* xb = reinterpret_cast<const f32x4*>(x) + (size_t)b * (CC * HW4);
    f32x4* ob = reinterpret_cast<f32x4*>(out) + (size_t)b * (CC * HW4);
    const f32x4* g4 = reinterpret_cast<const f32x4*>(gate);
    const int NP = R * W4;                      // 392 float4 per channel plane
    for (int i = t; i < CC * NP; i += T) {      // 25088 = 49 * 512
        int c  = i / NP;
        int p  = i - c * NP;
        int pr = p / W4;
        int pc = p - pr * W4;
        size_t off = (size_t)c * HW4 + (size_t)(h0 + pr) * W4 + pc;
        f32x4 v = xb[off];
        f32x4 g = g4[p];
        v *= g;
        __builtin_nontemporal_store(v, ob + off);
    }
}

extern "C" void kernel_launch(void* const* d_in, const int* in_sizes, int n_in,
                              void* d_out, int out_size, void* d_ws, size_t ws_size,
                              hipStream_t stream) {
    const float* x  = (const float*)d_in[0];   // [16,64,224,224]
    const float* cw = (const float*)d_in[1];   // [1,2,7,7]
    const float* cb = (const float*)d_in[2];   // [1]
    float* out  = (float*)d_out;
    float* feat = (float*)d_ws;                // 2 * 16 * 224 * 224 * 4 B = 6.4 MB

    reduce_kernel<<<NBLKA, TA, 0, stream>>>(x, feat);
    gate_kernel<<<NBLK, T, 0, stream>>>(x, feat, cw, cb, out);
}